// Round 8
// baseline (59.642 us; speedup 1.0000x reference)
//
#include <hip/hip_runtime.h>
#include <hip/hip_bf16.h>

#define B_    32
#define H_IN  80
#define T_IN  1600
#define C1_   32
#define H1_   40
#define T1_   800
#define C2_   32
#define H2_   20
#define T2_   400

// tile geometry: 4 h2 rows x 32 t2 cols per block, 4 waves (wave = output row)
// DIAGNOSTIC ROUND: grid.z = 4*B_ -> four identical copies of each block
// (benign duplicate writes of identical values) to (a) probe whether R7 is
// parallelism-bound and (b) push fused_conv above the 40us fill dispatches
// so rocprof top-5 shows its counters.
#define TH2   4
#define TT2   32
#define NH1   9            // 2*TH2+1 conv1 rows
#define NT1   65           // conv1 cols
#define NIDX  33           // ceil(NT1/2)
#define RROWS 19           // raw input rows (4*TH2+3)
#define RCOLSW 66          // raw cols in dwords (132 bf16)
#define RWORDS (RROWS * RCOLSW)   // 1254 dwords

#define NPOS   (NH1 * NT1)  // 585 conv1 positions
#define NCHUNK 19           // ceil(585/32)

#define WS_W2FRAGS 1152     // 9 tap * 2 half * 64 lane (32x32x16 A-frags)
#define WS_W1OFF   1152     // short8 index of W1 A-frag
#define WS_TOTAL   1216
#define OUTN  (B_ * C2_ * H2_ * T2_)

typedef unsigned int uint32;
typedef __attribute__((ext_vector_type(8)))  short short8;
typedef __attribute__((ext_vector_type(4)))  float f32x4;
typedef __attribute__((ext_vector_type(16))) float f32x16;
typedef __attribute__((ext_vector_type(2)))  uint32 u32x2;
typedef __attribute__((ext_vector_type(4)))  uint32 u32x4;

__device__ __forceinline__ unsigned short f2bf(float x) {
    __hip_bfloat16 h = __float2bfloat16(x);
    return __builtin_bit_cast(unsigned short, h);
}

// x1 LDS tile: parity-split on t1r + XOR swizzle of the 16B channel-chunk slot.
__device__ __forceinline__ int x1off(int h1r, int t1r, int g) {
    int idx = t1r >> 1;
    int par = t1r & 1;
    return ((par * (NH1 * NIDX) + h1r * NIDX + idx) << 6) + (((g ^ idx) & 3) << 4);
}

// ---- prep: W2 -> conv2 A-frags (32x32x16), W1+b1 -> conv1 A-frag (32x32x16) ----
__global__ void wprep(const float* __restrict__ W2, const float* __restrict__ W1,
                      const float* __restrict__ b1, unsigned short* __restrict__ ws) {
    int i = blockIdx.x * 256 + threadIdx.x;
    if (i < WS_W2FRAGS) {
        // i = (tap*2 + half)*64 + lane ; A: m=c2=lane&31, k=(lane>>5)*8+j (c1 within half)
        int th   = i >> 6;
        int lane = i & 63;
        int tap  = th >> 1;
        int half = th & 1;
        int c2   = lane & 31;
        int hi   = lane >> 5;
        short8 f;
#pragma unroll
        for (int j = 0; j < 8; ++j)
            f[j] = (short)f2bf(W2[(c2 * C1_ + half * 16 + hi * 8 + j) * 9 + tap]);
        *((short8*)ws + i) = f;
    } else if (i < WS_TOTAL) {
        // conv1 A-frag: lane l: m=c1=l&31, k=(l>>5)*8+j; k<9 -> W1 tap, k==9 -> bias, else 0
        int lane = i - WS_W1OFF;
        int c1 = lane & 31;
        int kb = (lane >> 5) * 8;
        short8 f;
#pragma unroll
        for (int j = 0; j < 8; ++j) {
            int k = kb + j;
            float v = (k < 9) ? W1[c1 * 9 + k] : (k == 9 ? b1[c1] : 0.0f);
            f[j] = (short)f2bf(v);
        }
        *((short8*)ws + i) = f;
    }
}

__global__ __launch_bounds__(256, 3) void fused_conv(
    const float* __restrict__ in, const int* __restrict__ seq,
    const float* __restrict__ b2,
    const unsigned short* __restrict__ ws,
    float* __restrict__ out)
{
    __shared__ __align__(16) char   x1mem[2 * NH1 * NIDX * 64];  // 38016 B
    __shared__ __align__(16) uint32 raw32[RWORDS];               // 5016 B

    const int tid  = threadIdx.x;
    const int lane = tid & 63;
    const int wv   = tid >> 6;
    const int hi   = lane >> 5;
    const int n32  = lane & 31;
    const int b      = blockIdx.z & (B_ - 1);   // 4 replicated copies (diagnostic)
    const int h2base = blockIdx.y * TH2;
    const int t2base = blockIdx.x * TT2;

    const int L  = seq[b];
    const int L1 = ((L  - 1) >> 1) + 1;
    const int L2 = ((L1 - 1) >> 1) + 1;

    if (blockIdx.x == 0 && blockIdx.y == 0 && blockIdx.z < B_ && tid == 0)
        out[OUTN + b] = (float)L2;

    // ---- early-out: whole t-tile beyond L2 -> zeros (float4 stores) ----
    if (t2base >= L2) {
        const f32x4 z4 = (f32x4){0.f, 0.f, 0.f, 0.f};
#pragma unroll
        for (int k = 0; k < 4; ++k) {
            int i = tid + k * 256;             // 128 rows (c2,r) x 8 quads
            int row = i >> 3, colq = i & 7;
            int c2 = row >> 2, r = row & 3;
            int t2q = t2base + colq * 4;
            if (t2q < T2_)
                *(f32x4*)(out + ((b * C2_ + c2) * H2_ + h2base + r) * T2_ + t2q) = z4;
        }
        return;
    }

    // ---- phase 0: stage raw tile as packed bf16 pairs (branch-free, coalesced) ----
    const int row0 = 4 * h2base - 3;
    const int t0   = 4 * t2base - 3;
    const float* inb = in + b * (H_IN * T_IN);
#pragma unroll
    for (int k = 0; k < 5; ++k) {
        int pi = tid + k * 256;
        if (pi < RWORDS) {
            int row = pi / RCOLSW;
            int q   = pi - row * RCOLSW;
            int h = row0 + row;
            int t = t0 + 2 * q;
            bool hok = (h >= 0) & (h < H_IN);
            bool ok0 = hok & (t >= 0) & (t < T_IN);
            bool ok1 = hok & (t + 1 >= 0) & (t + 1 < T_IN);
            float v0 = inb[ok0 ? h * T_IN + t     : 0];
            float v1 = inb[ok1 ? h * T_IN + t + 1 : 0];
            v0 = ok0 ? v0 : 0.0f;
            v1 = ok1 ? v1 : 0.0f;
            raw32[pi] = (uint32)f2bf(v0) | ((uint32)f2bf(v1) << 16);
        }
    }

    // prefetch conv1 weights + bias vectors (overlaps staging latency)
    const short8 w1f = *((const short8*)ws + WS_W1OFF + lane);
    f32x4 b2v4[4];
    {
        const f32x4* b2p = (const f32x4*)b2;
#pragma unroll
        for (int q = 0; q < 4; ++q) b2v4[q] = b2p[2 * q + hi];
    }

    __syncthreads();

    // ---- phase 1: conv1 via MFMA 32x32x16; chunk = 32 positions ----
    const int h1base = 2 * h2base - 1;
    const int t1base = 2 * t2base - 1;
    for (int c = wv; c < NCHUNK; c += 4) {
        int p  = c * 32 + n32;
        int pc = p < NPOS ? p : NPOS - 1;
        int h1r = pc / NT1;
        int t1r = pc - h1r * NT1;

        const uint32* rp = raw32 + (2 * h1r) * RCOLSW + t1r;
        uint32 a0 = rp[0],            b0v = rp[1];
        uint32 a1 = rp[RCOLSW],       b1v = rp[RCOLSW + 1];
        uint32 a2 = rp[2 * RCOLSW],   b2v = rp[2 * RCOLSW + 1];

        // lo lanes: k0..7 = taps (0,0),(0,1),(0,2),(1,0),(1,1),(1,2),(2,0),(2,1)
        uint32 w0l = a0;
        uint32 w1l = (b0v & 0xffffu) | (a1 << 16);
        uint32 w2l = (a1 >> 16) | (b1v << 16);
        uint32 w3l = a2;
        // hi lanes: k8 = tap (2,2), k9 = 1.0 (bias), rest 0
        uint32 w0h = (b2v & 0xffffu) | 0x3f800000u;

        uint32 fw0 = hi ? w0h : w0l;
        uint32 fw1 = hi ? 0u  : w1l;
        uint32 fw2 = hi ? 0u  : w2l;
        uint32 fw3 = hi ? 0u  : w3l;
        short8 bfrag = __builtin_bit_cast(short8, (u32x4){fw0, fw1, fw2, fw3});

        f32x16 acc = {};
        acc = __builtin_amdgcn_mfma_f32_32x32x16_bf16(w1f, bfrag, acc, 0, 0, 0);

        // epilogue: relu + mask -> bf16 -> x1 LDS (lane holds 16 channels of one position)
        int h1 = h1base + h1r;
        int t1 = t1base + t1r;
        bool okp = (h1 >= 0) && (t1 >= 0) && (t1 < L1);
        if (p < NPOS) {
#pragma unroll
            for (int g = 0; g < 4; ++g) {
                float v0 = okp ? fmaxf(acc[4 * g + 0], 0.0f) : 0.0f;
                float v1 = okp ? fmaxf(acc[4 * g + 1], 0.0f) : 0.0f;
                float v2 = okp ? fmaxf(acc[4 * g + 2], 0.0f) : 0.0f;
                float v3 = okp ? fmaxf(acc[4 * g + 3], 0.0f) : 0.0f;
                u32x2 dw;
                dw.x = (uint32)f2bf(v0) | ((uint32)f2bf(v1) << 16);
                dw.y = (uint32)f2bf(v2) | ((uint32)f2bf(v3) << 16);
                *(u32x2*)(x1mem + x1off(h1r, t1r, g) + hi * 8) = dw;
            }
        }
    }

    __syncthreads();

    // ---- phase 2: conv2 via MFMA 32x32x16, wave = output row r; direct stores ----
    const int r = wv;
    f32x16 acc = {};
#pragma unroll
    for (int tap = 0; tap < 9; ++tap) {
        const int kh = tap / 3;
        const int kt = tap % 3;
        const int t1r = 2 * n32 + kt;
#pragma unroll
        for (int half = 0; half < 2; ++half) {
            short8 a = *((const short8*)ws + (tap * 2 + half) * 64 + lane);
            short8 bx = *(const short8*)(x1mem + x1off(2 * r + kh, t1r, half * 2 + hi));
            acc = __builtin_amdgcn_mfma_f32_32x32x16_bf16(a, bx, acc, 0, 0, 0);
        }
    }

    // D layout: col = lane&31 = t2 within tile, row = (reg&3)+8*(reg>>2)+4*hi = c2
    const int t2 = t2base + n32;
    if (t2 < T2_) {
        const bool vm = (t2 < L2);
        float* outb = out + ((b * C2_) * H2_ + h2base + r) * T2_ + t2;
#pragma unroll
        for (int reg = 0; reg < 16; ++reg) {
            int c2 = (reg & 3) + 8 * (reg >> 2) + 4 * hi;
            float v = acc[reg] + b2v4[reg >> 2][reg & 3];
            v = vm ? fmaxf(v, 0.0f) : 0.0f;
            outb[c2 * (H2_ * T2_)] = v;
        }
    }
}

extern "C" void kernel_launch(void* const* d_in, const int* in_sizes, int n_in,
                              void* d_out, int out_size, void* d_ws, size_t ws_size,
                              hipStream_t stream) {
    const float* in  = (const float*)d_in[0];
    const int*   seq = (const int*)d_in[1];
    const float* W1  = (const float*)d_in[2];
    const float* b1  = (const float*)d_in[3];
    const float* W2  = (const float*)d_in[4];
    const float* b2  = (const float*)d_in[5];
    float* out = (float*)d_out;
    unsigned short* ws = (unsigned short*)d_ws;

    wprep<<<dim3((WS_TOTAL + 255) / 256), dim3(256), 0, stream>>>(W2, W1, b1, ws);

    // DIAGNOSTIC: 4x replicated grid (identical duplicate writes).
    dim3 grid((T2_ + TT2 - 1) / TT2, H2_ / TH2, 4 * B_);   // 13 x 5 x 128
    fused_conv<<<grid, dim3(256), 0, stream>>>(in, seq, b2, ws, out);
}

// Round 9
// 38.757 us; speedup vs baseline: 1.5389x; 1.5389x over previous
//
#include <hip/hip_runtime.h>
#include <hip/hip_bf16.h>

#define B_    32
#define H_IN  80
#define T_IN  1600
#define C1_   32
#define H1_   40
#define T1_   800
#define C2_   32
#define H2_   20
#define T2_   400

// tile geometry: 2 h2 rows x 32 t2 cols per tile; persistent blocks
#define TH2   2
#define TT2   32
#define NH1   5            // 2*TH2+1 conv1 rows
#define NT1   65           // conv1 cols
#define NIDX  33           // ceil(NT1/2)
#define RROWS 11           // raw input rows (4*TH2+3)
#define RCOLSW 66          // raw cols in dwords (132 bf16)
#define RWORDS (RROWS * RCOLSW)   // 726 dwords

#define NPOS   (NH1 * NT1)  // 325 conv1 positions
#define NCHUNK 11           // ceil(325/32)

#define NQ      130         // 13 t2-tiles * 10 h2-tiles per batch
#define NBLK    1280        // 5 blocks/CU * 256 CU, all resident
#define QSTRIDE (NBLK / B_) // 40

#define WS_W2FRAGS 1152     // 2 mt * 9 tap * 64 lane (16x16x32 A-frags)
#define WS_W1OFF   1152     // short8 index of W1 A-frag
#define WS_TOTAL   1216
#define OUTN  (B_ * C2_ * H2_ * T2_)

typedef unsigned int uint32;
typedef __attribute__((ext_vector_type(8)))  short short8;
typedef __attribute__((ext_vector_type(4)))  float f32x4;
typedef __attribute__((ext_vector_type(16))) float f32x16;
typedef __attribute__((ext_vector_type(2)))  uint32 u32x2;
typedef __attribute__((ext_vector_type(4)))  uint32 u32x4;

__device__ __forceinline__ unsigned short f2bf(float x) {
    __hip_bfloat16 h = __float2bfloat16(x);
    return __builtin_bit_cast(unsigned short, h);
}

// x1 LDS tile: parity-split on t1r + XOR swizzle of the 16B channel-chunk slot.
__device__ __forceinline__ int x1off(int h1r, int t1r, int g) {
    int idx = t1r >> 1;
    int par = t1r & 1;
    return ((par * (NH1 * NIDX) + h1r * NIDX + idx) << 6) + (((g ^ idx) & 3) << 4);
}

// staged raw-tile load into registers (T14 issue-early half)
__device__ __forceinline__ void stage_load(const float* __restrict__ inb, int tid,
                                           int h2base, int t2base, uint32 rv[3]) {
    const int row0 = 4 * h2base - 3;
    const int t0   = 4 * t2base - 3;
#pragma unroll
    for (int k = 0; k < 3; ++k) {
        int pi = tid + k * 256;
        uint32 v = 0u;
        if (pi < RWORDS) {
            int row = pi / RCOLSW;
            int qd  = pi - row * RCOLSW;
            int h = row0 + row;
            int t = t0 + 2 * qd;
            bool hok = (h >= 0) & (h < H_IN);
            bool ok0 = hok & (t >= 0) & (t < T_IN);
            bool ok1 = hok & (t + 1 >= 0) & (t + 1 < T_IN);
            float v0 = inb[ok0 ? h * T_IN + t     : 0];
            float v1 = inb[ok1 ? h * T_IN + t + 1 : 0];
            v0 = ok0 ? v0 : 0.0f;
            v1 = ok1 ? v1 : 0.0f;
            v = (uint32)f2bf(v0) | ((uint32)f2bf(v1) << 16);
        }
        rv[k] = v;
    }
}

// ---- prep: W2 -> conv2 A-frags (16x16x32), W1+b1 -> conv1 A-frag (32x32x16) ----
__global__ void wprep(const float* __restrict__ W2, const float* __restrict__ W1,
                      const float* __restrict__ b1, unsigned short* __restrict__ ws) {
    int i = blockIdx.x * 256 + threadIdx.x;
    if (i < WS_W2FRAGS) {
        int mt   = i / 576;
        int rem  = i - mt * 576;
        int tap  = rem >> 6;
        int lane = rem & 63;
        int lg   = lane >> 4;
        int l15  = lane & 15;
        int c2   = mt * 16 + l15;
        short8 f;
#pragma unroll
        for (int j = 0; j < 8; ++j)
            f[j] = (short)f2bf(W2[((c2 * C1_) + lg * 8 + j) * 9 + tap]);
        *((short8*)ws + i) = f;
    } else if (i < WS_TOTAL) {
        int lane = i - WS_W1OFF;
        int c1 = lane & 31;
        int kb = (lane >> 5) * 8;
        short8 f;
#pragma unroll
        for (int j = 0; j < 8; ++j) {
            int k = kb + j;
            float v = (k < 9) ? W1[c1 * 9 + k] : (k == 9 ? b1[c1] : 0.0f);
            f[j] = (short)f2bf(v);
        }
        *((short8*)ws + i) = f;
    }
}

__global__ __launch_bounds__(256, 5) void fused_conv(
    const float* __restrict__ in, const int* __restrict__ seq,
    const float* __restrict__ b2,
    const unsigned short* __restrict__ ws,
    float* __restrict__ out)
{
    __shared__ __align__(16) char   x1mem[2 * NH1 * NIDX * 64];  // 21120 B (reused as obuf)
    __shared__ __align__(16) uint32 raw32[RWORDS];               // 2904 B

    const int tid  = threadIdx.x;
    const int lane = tid & 63;
    const int wv   = tid >> 6;
    const int l15  = lane & 15;
    const int lg   = lane >> 4;
    const int hi   = lane >> 5;
    const int n32  = lane & 31;

    const int b  = blockIdx.x & (B_ - 1);   // fixed batch per block
    const int q0 = blockIdx.x >> 5;         // first tile index [0, QSTRIDE)

    const int L  = seq[b];
    const int L1 = ((L  - 1) >> 1) + 1;
    const int L2 = ((L1 - 1) >> 1) + 1;

    if (q0 == 0 && tid == 0)
        out[OUTN + b] = (float)L2;

    // hoisted weights (once per block, reused across tiles)
    const short8 w1f = *((const short8*)ws + WS_W1OFF + lane);
    const int mt    = wv & 1;
    const int strip = wv >> 1;
    short8 afr[9];
#pragma unroll
    for (int tap = 0; tap < 9; ++tap)
        afr[tap] = *((const short8*)ws + (mt * 9 + tap) * 64 + lane);
    float b2r[4];
#pragma unroll
    for (int j = 0; j < 4; ++j) b2r[j] = b2[mt * 16 + lg * 4 + j];

    const float* inb = in + b * (H_IN * T_IN);

    // prefetch first work tile (if any)
    uint32 rv[3];
    for (int q = q0; q < NQ; q += QSTRIDE) {
        int t2i = q / 10;
        if (t2i * TT2 < L2) {
            stage_load(inb, tid, (q - t2i * 10) * TH2, t2i * TT2, rv);
            break;
        }
    }

    for (int q = q0; q < NQ; q += QSTRIDE) {
        const int t2i = q / 10;
        const int h2i = q - t2i * 10;
        const int t2base = t2i * TT2;
        const int h2base = h2i * TH2;

        if (t2base >= L2) {
            // early-out tile: zero stores (no barriers, uniform per block)
            const f32x4 z4 = (f32x4){0.f, 0.f, 0.f, 0.f};
#pragma unroll
            for (int k = 0; k < 2; ++k) {
                int i = tid + k * 256;             // 64 rows (c2,r) x 8 quads
                int row = i >> 3, colq = i & 7;
                int c2 = row >> 1, r = row & 1;
                int t2q = t2base + colq * 4;
                if (t2q < T2_)
                    *(f32x4*)(out + ((b * C2_ + c2) * H2_ + h2base + r) * T2_ + t2q) = z4;
            }
            continue;
        }

        // ---- phase 0: write prefetched raw regs -> LDS ----
#pragma unroll
        for (int k = 0; k < 3; ++k) {
            int pi = tid + k * 256;
            if (pi < RWORDS) raw32[pi] = rv[k];
        }
        __syncthreads();

        // ---- phase 1: conv1 via MFMA 32x32x16 ----
        const int h1base = 2 * h2base - 1;
        const int t1base = 2 * t2base - 1;
        for (int c = wv; c < NCHUNK; c += 4) {
            int p  = c * 32 + n32;
            int pc = p < NPOS ? p : NPOS - 1;
            int h1r = pc / NT1;
            int t1r = pc - h1r * NT1;

            const uint32* rp = raw32 + (2 * h1r) * RCOLSW + t1r;
            uint32 a0 = rp[0],            b0v = rp[1];
            uint32 a1 = rp[RCOLSW],       b1v = rp[RCOLSW + 1];
            uint32 a2 = rp[2 * RCOLSW],   b2v = rp[2 * RCOLSW + 1];

            // lo lanes: k0..7 = taps (0,0),(0,1),(0,2),(1,0),(1,1),(1,2),(2,0),(2,1)
            uint32 w0l = a0;
            uint32 w1l = (b0v & 0xffffu) | (a1 << 16);
            uint32 w2l = (a1 >> 16) | (b1v << 16);
            uint32 w3l = a2;
            // hi lanes: k8 = tap (2,2), k9 = 1.0 (bias), rest 0
            uint32 w0h = (b2v & 0xffffu) | 0x3f800000u;

            uint32 fw0 = hi ? w0h : w0l;
            uint32 fw1 = hi ? 0u  : w1l;
            uint32 fw2 = hi ? 0u  : w2l;
            uint32 fw3 = hi ? 0u  : w3l;
            short8 bfrag = __builtin_bit_cast(short8, (u32x4){fw0, fw1, fw2, fw3});

            f32x16 acc = {};
            acc = __builtin_amdgcn_mfma_f32_32x32x16_bf16(w1f, bfrag, acc, 0, 0, 0);

            int h1 = h1base + h1r;
            int t1 = t1base + t1r;
            bool okp = (h1 >= 0) && (t1 >= 0) && (t1 < L1);
            if (p < NPOS) {
#pragma unroll
                for (int g = 0; g < 4; ++g) {
                    float v0 = okp ? fmaxf(acc[4 * g + 0], 0.0f) : 0.0f;
                    float v1 = okp ? fmaxf(acc[4 * g + 1], 0.0f) : 0.0f;
                    float v2 = okp ? fmaxf(acc[4 * g + 2], 0.0f) : 0.0f;
                    float v3 = okp ? fmaxf(acc[4 * g + 3], 0.0f) : 0.0f;
                    u32x2 dw;
                    dw.x = (uint32)f2bf(v0) | ((uint32)f2bf(v1) << 16);
                    dw.y = (uint32)f2bf(v2) | ((uint32)f2bf(v3) << 16);
                    *(u32x2*)(x1mem + x1off(h1r, t1r, g) + hi * 8) = dw;
                }
            }
        }
        __syncthreads();

        // ---- T14: issue next work-tile's raw loads (hide HBM under conv2) ----
        for (int q2 = q + QSTRIDE; q2 < NQ; q2 += QSTRIDE) {
            int tt = q2 / 10;
            if (tt * TT2 < L2) {
                stage_load(inb, tid, (q2 - tt * 10) * TH2, tt * TT2, rv);
                break;
            }
        }

        // ---- phase 2: conv2 implicit GEMM (16x16x32). wave = (strip, mt) ----
        f32x4 acc2[TH2];
#pragma unroll
        for (int r = 0; r < TH2; ++r) acc2[r] = (f32x4){0.f, 0.f, 0.f, 0.f};

#pragma unroll
        for (int tap = 0; tap < 9; ++tap) {
            const int kh = tap / 3;
            const int kt = tap % 3;
            const int t1r = 2 * (strip * 16 + l15) + kt;
#pragma unroll
            for (int r = 0; r < TH2; ++r) {
                short8 bx = *(const short8*)(x1mem + x1off(2 * r + kh, t1r, lg));
                acc2[r] = __builtin_amdgcn_mfma_f32_16x16x32_bf16(afr[tap], bx, acc2[r], 0, 0, 0);
            }
        }
        __syncthreads();   // x1 reads done; reuse x1mem as obuf [64 rows][33]

        // D layout: col(l15)=t2 within strip, row=(lg*4+j)=c2 within mtile
        float* obuf = (float*)x1mem;
        {
            const int t2 = t2base + strip * 16 + l15;
            const bool vm = (t2 < L2);
#pragma unroll
            for (int r = 0; r < TH2; ++r) {
#pragma unroll
                for (int j = 0; j < 4; ++j) {
                    int c2 = mt * 16 + lg * 4 + j;
                    float v = acc2[r][j] + b2r[j];
                    v = vm ? fmaxf(v, 0.0f) : 0.0f;
                    obuf[(c2 * TH2 + r) * 33 + strip * 16 + l15] = v;
                }
            }
        }
        __syncthreads();

        // coalesced fp32 stores: 128B segments. (Next iteration's phase-0
        // barrier orders these obuf reads against the next conv1 x1 writes.)
#pragma unroll
        for (int k = 0; k < 8; ++k) {
            int i = tid + k * 256;                  // 64 rows x 32 cols
            int row = i >> 5, col = i & 31;
            int c2 = row >> 1, r = row & 1;
            int t2 = t2base + col;
            if (t2 < T2_)
                out[((b * C2_ + c2) * H2_ + h2base + r) * T2_ + t2] = obuf[row * 33 + col];
        }
    }
}

extern "C" void kernel_launch(void* const* d_in, const int* in_sizes, int n_in,
                              void* d_out, int out_size, void* d_ws, size_t ws_size,
                              hipStream_t stream) {
    const float* in  = (const float*)d_in[0];
    const int*   seq = (const int*)d_in[1];
    const float* W1  = (const float*)d_in[2];
    const float* b1  = (const float*)d_in[3];
    const float* W2  = (const float*)d_in[4];
    const float* b2  = (const float*)d_in[5];
    float* out = (float*)d_out;
    unsigned short* ws = (unsigned short*)d_ws;

    wprep<<<dim3((WS_TOTAL + 255) / 256), dim3(256), 0, stream>>>(W2, W1, b1, ws);

    fused_conv<<<dim3(NBLK), dim3(256), 0, stream>>>(in, seq, b2, ws, out);
}

// Round 10
// 28.046 us; speedup vs baseline: 2.1266x; 1.3819x over previous
//
#include <hip/hip_runtime.h>
#include <hip/hip_bf16.h>

#define B_    32
#define H_IN  80
#define T_IN  1600
#define C1_   32
#define H1_   40
#define T1_   800
#define C2_   32
#define H2_   20
#define T2_   400

// wave-private subtile: 16 t2 x 1 h2.  Block = 4 waves = 64 t2 x 1 h2.
// Per-wave LDS region: x1 tile (3 h1 x 33 t1 x 32 c1 bf16, parity+XOR swizzled)
// at [0,6528) reused as obuf (32 c2 x 16 t2 fp32 = 2048B), raw bf16-pair tile
// (7 rows x 34 dwords) at [6528, 7480). Stride 7584 (=32 mod 128 -> bank skew).
#define WSTRIDE 7584
#define RAWOFF  6528
#define RCW     34          // raw dwords per row
#define RWTOT   238         // 7 * 34
#define NPOSW   99          // 3 * 33 conv1 positions per wave
#define OUTN  (B_ * C2_ * H2_ * T2_)

#define WS_W2FRAGS 1152     // 2 mt * 9 tap * 64 lane (16x16x32 A-frags)
#define WS_W1OFF   1152
#define WS_TOTAL   1216

typedef unsigned int uint32;
typedef __attribute__((ext_vector_type(8)))  short short8;
typedef __attribute__((ext_vector_type(4)))  float f32x4;
typedef __attribute__((ext_vector_type(16))) float f32x16;
typedef __attribute__((ext_vector_type(2)))  uint32 u32x2;
typedef __attribute__((ext_vector_type(4)))  uint32 u32x4;

__device__ __forceinline__ unsigned short f2bf(float x) {
    __hip_bfloat16 h = __float2bfloat16(x);
    return __builtin_bit_cast(unsigned short, h);
}

// x1 offset within a wave's region (17 idx slots, parity split, XOR chunk swizzle)
__device__ __forceinline__ int x1off(int h1r, int t1r, int g) {
    int idx = t1r >> 1;
    int par = t1r & 1;
    return ((par * 51 + h1r * 17 + idx) << 6) + (((g ^ idx) & 3) << 4);
}

// ---- prep: W2 -> conv2 A-frags (16x16x32), W1+b1 -> conv1 A-frag (32x32x16) ----
__global__ void wprep(const float* __restrict__ W2, const float* __restrict__ W1,
                      const float* __restrict__ b1, unsigned short* __restrict__ ws) {
    int i = blockIdx.x * 256 + threadIdx.x;
    if (i < WS_W2FRAGS) {
        int mt   = i / 576;
        int rem  = i - mt * 576;
        int tap  = rem >> 6;
        int lane = rem & 63;
        int lg   = lane >> 4;
        int l15  = lane & 15;
        int c2   = mt * 16 + l15;
        short8 f;
#pragma unroll
        for (int j = 0; j < 8; ++j)
            f[j] = (short)f2bf(W2[((c2 * C1_) + lg * 8 + j) * 9 + tap]);
        *((short8*)ws + i) = f;
    } else if (i < WS_TOTAL) {
        int lane = i - WS_W1OFF;
        int c1 = lane & 31;
        int kb = (lane >> 5) * 8;
        short8 f;
#pragma unroll
        for (int j = 0; j < 8; ++j) {
            int k = kb + j;
            float v = (k < 9) ? W1[c1 * 9 + k] : (k == 9 ? b1[c1] : 0.0f);
            f[j] = (short)f2bf(v);
        }
        *((short8*)ws + i) = f;
    }
}

__global__ __launch_bounds__(256, 5) void fused_conv(
    const float* __restrict__ in, const int* __restrict__ seq,
    const float* __restrict__ b2,
    const unsigned short* __restrict__ ws,
    float* __restrict__ out)
{
    __shared__ __align__(16) char lds[4 * WSTRIDE];   // 30336 B

    const int tid  = threadIdx.x;
    const int lane = tid & 63;
    const int wv   = tid >> 6;
    const int l15  = lane & 15;
    const int lg   = lane >> 4;
    const int hi   = lane >> 5;
    const int n32  = lane & 31;
    const int b    = blockIdx.z;
    const int h2   = blockIdx.y;
    const int t2q  = blockIdx.x;          // 64-wide t2 super-tile

    const int L  = seq[b];
    const int L1 = ((L  - 1) >> 1) + 1;
    const int L2 = ((L1 - 1) >> 1) + 1;

    if (t2q == 0 && h2 == 0 && tid == 0)
        out[OUTN + b] = (float)L2;

    // ---- block-level early-out: whole 64-col super-tile beyond L2 ----
    if (64 * t2q >= L2) {
        const f32x4 z4 = (f32x4){0.f, 0.f, 0.f, 0.f};
#pragma unroll
        for (int k = 0; k < 2; ++k) {
            int i = tid + k * 256;        // 32 c2 x 16 quads
            int c2 = i >> 4, q = i & 15;
            int t2g = 64 * t2q + 4 * q;
            if (t2g < T2_)
                *(f32x4*)(out + ((b * C2_ + c2) * H2_ + h2) * T2_ + t2g) = z4;
        }
        return;
    }

    char*   myl = lds + wv * WSTRIDE;
    uint32* raw = (uint32*)(myl + RAWOFF);
    const int t2i    = t2q * 4 + wv;
    const int t2base = t2i * 16;
    const bool wave_zero = (t2base >= L2);   // includes dead waves (t2base >= 400)

    const short8 w1f = *((const short8*)ws + WS_W1OFF + lane);

    if (!wave_zero) {
        // ---- stage raw tile (wave-private, branch-free, packed bf16 pairs) ----
        const int row0 = 4 * h2 - 3;
        const int t0   = 64 * t2i - 3;
        const float* inb = in + b * (H_IN * T_IN);
#pragma unroll
        for (int k = 0; k < 4; ++k) {
            int idx = lane + 64 * k;
            if (idx < RWTOT) {
                int row = idx / RCW;
                int q   = idx - row * RCW;
                int h = row0 + row;
                int t = t0 + 2 * q;
                bool hok = (h >= 0) & (h < H_IN);
                bool ok0 = hok & (t >= 0) & (t < T_IN);
                bool ok1 = hok & (t + 1 >= 0) & (t + 1 < T_IN);
                float v0 = inb[ok0 ? h * T_IN + t     : 0];
                float v1 = inb[ok1 ? h * T_IN + t + 1 : 0];
                v0 = ok0 ? v0 : 0.0f;
                v1 = ok1 ? v1 : 0.0f;
                raw[row * RCW + q] = (uint32)f2bf(v0) | ((uint32)f2bf(v1) << 16);
            }
        }
        // no barrier: same-wave LDS dependency, hardware waitcnt suffices

        // ---- conv1 via MFMA 32x32x16: 4 chunks of 32 positions ----
#pragma unroll
        for (int c = 0; c < 4; ++c) {
            int p  = c * 32 + n32;
            int pc = p < NPOSW ? p : NPOSW - 1;
            int h1r = pc / 33;
            int t1r = pc - 33 * h1r;

            const uint32* rp = raw + (2 * h1r) * RCW + t1r;
            uint32 r0a = rp[0],           r0b = rp[1];
            uint32 r1a = rp[RCW],         r1b = rp[RCW + 1];
            uint32 r2a = rp[2 * RCW],     r2b = rp[2 * RCW + 1];

            // lo lanes: k0..7 = taps (0,0),(0,1),(0,2),(1,0),(1,1),(1,2),(2,0),(2,1)
            uint32 w0l = r0a;
            uint32 w1l = (r0b & 0xffffu) | (r1a << 16);
            uint32 w2l = (r1a >> 16) | (r1b << 16);
            uint32 w3l = r2a;
            // hi lanes: k8 = tap (2,2), k9 = 1.0 (bias)
            uint32 w0h = (r2b & 0xffffu) | 0x3f800000u;

            uint32 fw0 = hi ? w0h : w0l;
            uint32 fw1 = hi ? 0u  : w1l;
            uint32 fw2 = hi ? 0u  : w2l;
            uint32 fw3 = hi ? 0u  : w3l;
            short8 bfrag = __builtin_bit_cast(short8, (u32x4){fw0, fw1, fw2, fw3});

            f32x16 acc = {};
            acc = __builtin_amdgcn_mfma_f32_32x32x16_bf16(w1f, bfrag, acc, 0, 0, 0);

            int h1 = 2 * h2 - 1 + h1r;
            int t1 = 32 * t2i - 1 + t1r;
            bool okp = (h1 >= 0) && (t1 >= 0) && (t1 < L1);
            if (p < NPOSW) {
#pragma unroll
                for (int g = 0; g < 4; ++g) {
                    float v0 = okp ? fmaxf(acc[4 * g + 0], 0.0f) : 0.0f;
                    float v1 = okp ? fmaxf(acc[4 * g + 1], 0.0f) : 0.0f;
                    float v2 = okp ? fmaxf(acc[4 * g + 2], 0.0f) : 0.0f;
                    float v3 = okp ? fmaxf(acc[4 * g + 3], 0.0f) : 0.0f;
                    u32x2 dw;
                    dw.x = (uint32)f2bf(v0) | ((uint32)f2bf(v1) << 16);
                    dw.y = (uint32)f2bf(v2) | ((uint32)f2bf(v3) << 16);
                    *(u32x2*)(myl + x1off(h1r, t1r, g) + hi * 8) = dw;
                }
            }
        }

        // ---- conv2 via MFMA 16x16x32 (wave-private x1), lazy A-frag loads ----
        f32x4 acc2[2];
        acc2[0] = (f32x4){0.f, 0.f, 0.f, 0.f};
        acc2[1] = (f32x4){0.f, 0.f, 0.f, 0.f};
#pragma unroll
        for (int tap = 0; tap < 9; ++tap) {
            const int kh = tap / 3;
            const int kt = tap % 3;
            const int t1r = 2 * l15 + kt;
            short8 bx  = *(const short8*)(myl + x1off(kh, t1r, lg));
            short8 af0 = *((const short8*)ws + tap * 64 + lane);
            short8 af1 = *((const short8*)ws + (9 + tap) * 64 + lane);
            acc2[0] = __builtin_amdgcn_mfma_f32_16x16x32_bf16(af0, bx, acc2[0], 0, 0, 0);
            acc2[1] = __builtin_amdgcn_mfma_f32_16x16x32_bf16(af1, bx, acc2[1], 0, 0, 0);
        }

        // ---- epilogue: bias + mask + relu -> wave obuf (reuse x1 area) ----
        // D layout: col = l15 = t2 within subtile, row = lg*4+j = c2 within mtile
        float* obuf = (float*)myl;
        const int t2 = t2base + l15;
        const bool vm = (t2 < L2);
        const f32x4* b2p = (const f32x4*)b2;
#pragma unroll
        for (int mt = 0; mt < 2; ++mt) {
            f32x4 bb = b2p[mt * 4 + lg];
#pragma unroll
            for (int j = 0; j < 4; ++j) {
                int c2 = mt * 16 + lg * 4 + j;
                float v = acc2[mt][j] + bb[j];
                v = vm ? fmaxf(v, 0.0f) : 0.0f;
                obuf[c2 * 16 + l15] = v;
            }
        }
    } else {
        // masked / dead wave: zero obuf
        u32x2* ob = (u32x2*)myl;
        const u32x2 z = (u32x2){0u, 0u};
#pragma unroll
        for (int k = 0; k < 4; ++k) ob[lane + 64 * k] = z;
    }

    __syncthreads();   // the ONLY barrier: obufs ready for cooperative store

    // ---- cooperative store: 4 adjacent subtiles -> 256B segments ----
#pragma unroll
    for (int k = 0; k < 8; ++k) {
        int i = tid + k * 256;            // 32 c2 rows x 64 cols
        int c2 = i >> 6, col = i & 63;
        int wsel = col >> 4;
        int t2g = 64 * t2q + col;
        float f = *(const float*)(lds + wsel * WSTRIDE + (c2 * 16 + (col & 15)) * 4);
        if (t2g < T2_)
            out[((b * C2_ + c2) * H2_ + h2) * T2_ + t2g] = f;
    }
}

extern "C" void kernel_launch(void* const* d_in, const int* in_sizes, int n_in,
                              void* d_out, int out_size, void* d_ws, size_t ws_size,
                              hipStream_t stream) {
    const float* in  = (const float*)d_in[0];
    const int*   seq = (const int*)d_in[1];
    const float* W1  = (const float*)d_in[2];
    const float* b1  = (const float*)d_in[3];
    const float* W2  = (const float*)d_in[4];
    const float* b2  = (const float*)d_in[5];
    float* out = (float*)d_out;
    unsigned short* ws = (unsigned short*)d_ws;

    wprep<<<dim3((WS_TOTAL + 255) / 256), dim3(256), 0, stream>>>(W2, W1, b1, ws);

    dim3 grid(7, H2_, B_);   // t2 super-tiles of 64, h2 rows, batch
    fused_conv<<<grid, dim3(256), 0, stream>>>(in, seq, b2, ws, out);
}

// Round 11
// 27.158 us; speedup vs baseline: 2.1961x; 1.0327x over previous
//
#include <hip/hip_runtime.h>
#include <hip/hip_bf16.h>

#define B_    32
#define H_IN  80
#define T_IN  1600
#define C1_   32
#define H1_   40
#define T1_   800
#define C2_   32
#define H2_   20
#define T2_   400

// wave-private subtile: 16 t2 x 2 h2.  Block = 4 waves = 64 t2 x 2 h2.
// Per-wave LDS: x1 tile (5 h1 x 33 t1 x 32c bf16, parity+XOR swizzle) at [0,10880)
// (reused as obuf 32c2 x 2r x 16t2 fp32 = 4KB), raw bf16-pair tile (11 rows x 34
// dwords) at [10880, 12376). WSTRIDE 12448 (mod 128 = 32 -> bank skew).
#define WSTRIDE 12448
#define RAWOFF  10880
#define RCW     34          // raw dwords per row
#define RWTOT   374         // 11 * 34
#define NPOSW   165         // 5 * 33 conv1 positions per wave
#define OUTN  (B_ * C2_ * H2_ * T2_)

#define WS_W2FRAGS 1152     // 2 mt * 9 tap * 64 lane (16x16x32 A-frags)
#define WS_W1OFF   1152
#define WS_TOTAL   1216

typedef unsigned int uint32;
typedef __attribute__((ext_vector_type(8)))  short short8;
typedef __attribute__((ext_vector_type(4)))  float f32x4;
typedef __attribute__((ext_vector_type(16))) float f32x16;
typedef __attribute__((ext_vector_type(2)))  uint32 u32x2;
typedef __attribute__((ext_vector_type(4)))  uint32 u32x4;

__device__ __forceinline__ unsigned short f2bf(float x) {
    __hip_bfloat16 h = __float2bfloat16(x);
    return __builtin_bit_cast(unsigned short, h);
}

// x1 offset within a wave's region: 5 h1 rows x 17 idx slots, parity split, XOR swizzle
__device__ __forceinline__ int x1off(int h1r, int t1r, int g) {
    int idx = t1r >> 1;
    int par = t1r & 1;
    return ((par * 85 + h1r * 17 + idx) << 6) + (((g ^ idx) & 3) << 4);
}

// ---- prep: W2 -> conv2 A-frags (16x16x32), W1+b1 -> conv1 A-frag (32x32x16) ----
__global__ void wprep(const float* __restrict__ W2, const float* __restrict__ W1,
                      const float* __restrict__ b1, unsigned short* __restrict__ ws) {
    int i = blockIdx.x * 256 + threadIdx.x;
    if (i < WS_W2FRAGS) {
        int mt   = i / 576;
        int rem  = i - mt * 576;
        int tap  = rem >> 6;
        int lane = rem & 63;
        int lg   = lane >> 4;
        int l15  = lane & 15;
        int c2   = mt * 16 + l15;
        short8 f;
#pragma unroll
        for (int j = 0; j < 8; ++j)
            f[j] = (short)f2bf(W2[((c2 * C1_) + lg * 8 + j) * 9 + tap]);
        *((short8*)ws + i) = f;
    } else if (i < WS_TOTAL) {
        int lane = i - WS_W1OFF;
        int c1 = lane & 31;
        int kb = (lane >> 5) * 8;
        short8 f;
#pragma unroll
        for (int j = 0; j < 8; ++j) {
            int k = kb + j;
            float v = (k < 9) ? W1[c1 * 9 + k] : (k == 9 ? b1[c1] : 0.0f);
            f[j] = (short)f2bf(v);
        }
        *((short8*)ws + i) = f;
    }
}

__global__ __launch_bounds__(256, 3) void fused_conv(
    const float* __restrict__ in, const int* __restrict__ seq,
    const float* __restrict__ b2,
    const unsigned short* __restrict__ ws,
    float* __restrict__ out)
{
    __shared__ __align__(16) char lds[4 * WSTRIDE];   // 49792 B

    const int tid  = threadIdx.x;
    const int lane = tid & 63;
    const int wv   = tid >> 6;
    const int l15  = lane & 15;
    const int lg   = lane >> 4;
    const int hi   = lane >> 5;
    const int n32  = lane & 31;
    const int b      = blockIdx.z;
    const int h2base = blockIdx.y * 2;
    const int t2q    = blockIdx.x;        // 64-wide t2 super-tile

    const int L  = seq[b];
    const int L1 = ((L  - 1) >> 1) + 1;
    const int L2 = ((L1 - 1) >> 1) + 1;

    if (t2q == 0 && blockIdx.y == 0 && tid == 0)
        out[OUTN + b] = (float)L2;

    // ---- block-level early-out: whole 64-col super-tile beyond L2 ----
    if (64 * t2q >= L2) {
        const f32x4 z4 = (f32x4){0.f, 0.f, 0.f, 0.f};
#pragma unroll
        for (int k = 0; k < 4; ++k) {
            int i = tid + k * 256;        // 64 (c2,r) rows x 16 quads
            int row = i >> 4, q = i & 15;
            int c2 = row >> 1, r = row & 1;
            int t2g = 64 * t2q + 4 * q;
            if (t2g < T2_)
                *(f32x4*)(out + ((b * C2_ + c2) * H2_ + h2base + r) * T2_ + t2g) = z4;
        }
        return;
    }

    char*   myl = lds + wv * WSTRIDE;
    uint32* raw = (uint32*)(myl + RAWOFF);
    const int t2i    = t2q * 4 + wv;
    const int t2base = t2i * 16;
    const bool wave_zero = (t2base >= L2);   // masked or beyond T2

    // hoisted weight frags (uniform loads, L2-hot)
    const short8 w1f = *((const short8*)ws + WS_W1OFF + lane);
    short8 afr[18];
#pragma unroll
    for (int tap = 0; tap < 18; ++tap)
        afr[tap] = *((const short8*)ws + tap * 64 + lane);

    if (!wave_zero) {
        // ---- stage raw tile (wave-private, branch-free, packed bf16 pairs) ----
        const int row0 = 4 * h2base - 3;
        const int t0   = 4 * t2base - 3;
        const float* inb = in + b * (H_IN * T_IN);
#pragma unroll
        for (int k = 0; k < 6; ++k) {
            int idx = lane + 64 * k;
            if (idx < RWTOT) {
                int row = idx / RCW;
                int q   = idx - row * RCW;
                int h = row0 + row;
                int t = t0 + 2 * q;
                bool hok = (h >= 0) & (h < H_IN);
                bool ok0 = hok & (t >= 0) & (t < T_IN);
                bool ok1 = hok & (t + 1 >= 0) & (t + 1 < T_IN);
                float v0 = inb[ok0 ? h * T_IN + t     : 0];
                float v1 = inb[ok1 ? h * T_IN + t + 1 : 0];
                v0 = ok0 ? v0 : 0.0f;
                v1 = ok1 ? v1 : 0.0f;
                raw[row * RCW + q] = (uint32)f2bf(v0) | ((uint32)f2bf(v1) << 16);
            }
        }
        // no barrier: same-wave LDS dependency, hardware waitcnt suffices

        // ---- conv1 via MFMA 32x32x16: 6 chunks of 32 positions (independent) ----
#pragma unroll
        for (int c = 0; c < 6; ++c) {
            int p  = c * 32 + n32;
            int pc = p < NPOSW ? p : NPOSW - 1;
            int h1r = pc / 33;
            int t1r = pc - 33 * h1r;

            const uint32* rp = raw + (2 * h1r) * RCW + t1r;
            uint32 r0a = rp[0],           r0b = rp[1];
            uint32 r1a = rp[RCW],         r1b = rp[RCW + 1];
            uint32 r2a = rp[2 * RCW],     r2b = rp[2 * RCW + 1];

            // lo lanes: k0..7 = taps (0,0),(0,1),(0,2),(1,0),(1,1),(1,2),(2,0),(2,1)
            uint32 w0l = r0a;
            uint32 w1l = (r0b & 0xffffu) | (r1a << 16);
            uint32 w2l = (r1a >> 16) | (r1b << 16);
            uint32 w3l = r2a;
            // hi lanes: k8 = tap (2,2), k9 = 1.0 (bias)
            uint32 w0h = (r2b & 0xffffu) | 0x3f800000u;

            uint32 fw0 = hi ? w0h : w0l;
            uint32 fw1 = hi ? 0u  : w1l;
            uint32 fw2 = hi ? 0u  : w2l;
            uint32 fw3 = hi ? 0u  : w3l;
            short8 bfrag = __builtin_bit_cast(short8, (u32x4){fw0, fw1, fw2, fw3});

            f32x16 acc = {};
            acc = __builtin_amdgcn_mfma_f32_32x32x16_bf16(w1f, bfrag, acc, 0, 0, 0);

            int h1 = 2 * h2base - 1 + h1r;
            int t1 = 2 * t2base - 1 + t1r;
            bool okp = (h1 >= 0) && (t1 >= 0) && (t1 < L1);
            if (p < NPOSW) {
#pragma unroll
                for (int g = 0; g < 4; ++g) {
                    float v0 = okp ? fmaxf(acc[4 * g + 0], 0.0f) : 0.0f;
                    float v1 = okp ? fmaxf(acc[4 * g + 1], 0.0f) : 0.0f;
                    float v2 = okp ? fmaxf(acc[4 * g + 2], 0.0f) : 0.0f;
                    float v3 = okp ? fmaxf(acc[4 * g + 3], 0.0f) : 0.0f;
                    u32x2 dw;
                    dw.x = (uint32)f2bf(v0) | ((uint32)f2bf(v1) << 16);
                    dw.y = (uint32)f2bf(v2) | ((uint32)f2bf(v3) << 16);
                    *(u32x2*)(myl + x1off(h1r, t1r, g) + hi * 8) = dw;
                }
            }
        }

        // ---- conv2 via MFMA 16x16x32, both h2 rows, both m-tiles ----
        f32x4 acc00 = (f32x4){0.f,0.f,0.f,0.f}, acc10 = acc00;
        f32x4 acc01 = acc00, acc11 = acc00;
#pragma unroll
        for (int tap = 0; tap < 9; ++tap) {
            const int kh = tap / 3;
            const int kt = tap % 3;
            const int t1r = 2 * l15 + kt;
            short8 bx0 = *(const short8*)(myl + x1off(kh,     t1r, lg));
            short8 bx1 = *(const short8*)(myl + x1off(kh + 2, t1r, lg));
            acc00 = __builtin_amdgcn_mfma_f32_16x16x32_bf16(afr[tap],     bx0, acc00, 0, 0, 0);
            acc10 = __builtin_amdgcn_mfma_f32_16x16x32_bf16(afr[9 + tap], bx0, acc10, 0, 0, 0);
            acc01 = __builtin_amdgcn_mfma_f32_16x16x32_bf16(afr[tap],     bx1, acc01, 0, 0, 0);
            acc11 = __builtin_amdgcn_mfma_f32_16x16x32_bf16(afr[9 + tap], bx1, acc11, 0, 0, 0);
        }

        // ---- epilogue: bias + mask + relu -> wave obuf (reuse x1 area) ----
        // D layout: col = l15 = t2 within subtile, row = lg*4+j = c2 within mtile
        float* obuf = (float*)myl;
        const int t2 = t2base + l15;
        const bool vm = (t2 < L2);
        const f32x4* b2p = (const f32x4*)b2;
        f32x4 bb0 = b2p[lg], bb1 = b2p[4 + lg];
#pragma unroll
        for (int j = 0; j < 4; ++j) {
            int c2a = lg * 4 + j;
            int c2b = 16 + c2a;
            float v00 = vm ? fmaxf(acc00[j] + bb0[j], 0.0f) : 0.0f;
            float v01 = vm ? fmaxf(acc01[j] + bb0[j], 0.0f) : 0.0f;
            float v10 = vm ? fmaxf(acc10[j] + bb1[j], 0.0f) : 0.0f;
            float v11 = vm ? fmaxf(acc11[j] + bb1[j], 0.0f) : 0.0f;
            obuf[(c2a * 2 + 0) * 16 + l15] = v00;
            obuf[(c2a * 2 + 1) * 16 + l15] = v01;
            obuf[(c2b * 2 + 0) * 16 + l15] = v10;
            obuf[(c2b * 2 + 1) * 16 + l15] = v11;
        }
    } else {
        // masked / dead wave: zero obuf (1024 dwords)
        u32x2* ob = (u32x2*)myl;
        const u32x2 z = (u32x2){0u, 0u};
#pragma unroll
        for (int k = 0; k < 8; ++k) ob[lane + 64 * k] = z;
    }

    __syncthreads();   // the ONLY barrier: obufs ready for cooperative store

    // ---- cooperative store: 4 adjacent subtiles -> 256B segments ----
#pragma unroll
    for (int k = 0; k < 16; ++k) {
        int i = tid + k * 256;            // 64 (c2,r) rows x 64 cols
        int row = i >> 6, col = i & 63;
        int c2 = row >> 1, r = row & 1;
        int t2g = 64 * t2q + col;
        float f = *(const float*)(lds + (col >> 4) * WSTRIDE + ((row << 4) + (col & 15)) * 4);
        if (t2g < T2_)
            out[((b * C2_ + c2) * H2_ + h2base + r) * T2_ + t2g] = f;
    }
}

extern "C" void kernel_launch(void* const* d_in, const int* in_sizes, int n_in,
                              void* d_out, int out_size, void* d_ws, size_t ws_size,
                              hipStream_t stream) {
    const float* in  = (const float*)d_in[0];
    const int*   seq = (const int*)d_in[1];
    const float* W1  = (const float*)d_in[2];
    const float* b1  = (const float*)d_in[3];
    const float* W2  = (const float*)d_in[4];
    const float* b2  = (const float*)d_in[5];
    float* out = (float*)d_out;
    unsigned short* ws = (unsigned short*)d_ws;

    wprep<<<dim3((WS_TOTAL + 255) / 256), dim3(256), 0, stream>>>(W2, W1, b1, ws);

    dim3 grid(7, H2_ / 2, B_);   // t2 super-tiles of 64, h2 pairs, batch
    fused_conv<<<grid, dim3(256), 0, stream>>>(in, seq, b2, ws, out);
}

// Round 12
// 23.740 us; speedup vs baseline: 2.5123x; 1.1440x over previous
//
#include <hip/hip_runtime.h>
#include <hip/hip_bf16.h>

#define B_    32
#define H_IN  80
#define T_IN  1600
#define C1_   32
#define H1_   40
#define T1_   800
#define C2_   32
#define H2_   20
#define T2_   400

// tile geometry: 2 h2 rows x 32 t2 cols per block
#define TH2   2
#define TT2   32
#define NH1   5            // 2*TH2+1 conv1 rows
#define NT1   65           // conv1 cols
#define NIDX  33           // ceil(NT1/2)
#define RROWS 11           // raw input rows (4*TH2+3)
#define RCOLSW 66          // raw cols in dwords (132 bf16)
#define RWORDS (RROWS * RCOLSW)   // 726 dwords

#define NPOS   (NH1 * NT1)  // 325 conv1 positions
#define NCHUNK 11           // ceil(325/32)

#define WS_W2FRAGS 1152     // 2 mt * 9 tap * 64 lane (16x16x32 A-frags)
#define WS_W1OFF   1152     // short8 index of W1 A-frags
#define WS_TOTAL   1216
#define OUTN  (B_ * C2_ * H2_ * T2_)

#define OSTR  36            // obuf row stride (floats); 36*4=144B keeps quads 16B-aligned

typedef unsigned int uint32;
typedef __attribute__((ext_vector_type(8)))  short short8;
typedef __attribute__((ext_vector_type(4)))  float f32x4;
typedef __attribute__((ext_vector_type(16))) float f32x16;
typedef __attribute__((ext_vector_type(2)))  uint32 u32x2;
typedef __attribute__((ext_vector_type(4)))  uint32 u32x4;

__device__ __forceinline__ unsigned short f2bf(float x) {
    __hip_bfloat16 h = __float2bfloat16(x);
    return __builtin_bit_cast(unsigned short, h);
}

// x1 LDS tile: parity-split on t1r + XOR swizzle of the 16B channel-chunk slot.
__device__ __forceinline__ int x1off(int h1r, int t1r, int g) {
    int idx = t1r >> 1;
    int par = t1r & 1;
    return ((par * (NH1 * NIDX) + h1r * NIDX + idx) << 6) + (((g ^ idx) & 3) << 4);
}

// ---- prep: W2 -> conv2 A-frags (16x16x32), W1+b1 -> conv1 A-frag (32x32x16) ----
__global__ void wprep(const float* __restrict__ W2, const float* __restrict__ W1,
                      const float* __restrict__ b1, unsigned short* __restrict__ ws) {
    int i = blockIdx.x * 256 + threadIdx.x;
    if (i < WS_W2FRAGS) {
        int mt   = i / 576;
        int rem  = i - mt * 576;
        int tap  = rem >> 6;
        int lane = rem & 63;
        int lg   = lane >> 4;
        int l15  = lane & 15;
        int c2   = mt * 16 + l15;
        short8 f;
#pragma unroll
        for (int j = 0; j < 8; ++j)
            f[j] = (short)f2bf(W2[((c2 * C1_) + lg * 8 + j) * 9 + tap]);
        *((short8*)ws + i) = f;
    } else if (i < WS_TOTAL) {
        int lane = i - WS_W1OFF;
        int c1 = lane & 31;
        int kb = (lane >> 5) * 8;
        short8 f;
#pragma unroll
        for (int j = 0; j < 8; ++j) {
            int k = kb + j;
            float v = (k < 9) ? W1[c1 * 9 + k] : (k == 9 ? b1[c1] : 0.0f);
            f[j] = (short)f2bf(v);
        }
        *((short8*)ws + i) = f;
    }
}

__global__ __launch_bounds__(256, 6) void fused_conv(
    const float* __restrict__ in, const int* __restrict__ seq,
    const float* __restrict__ b2,
    const unsigned short* __restrict__ ws,
    float* __restrict__ out)
{
    __shared__ __align__(16) char   x1mem[2 * NH1 * NIDX * 64];  // 21120 B (reused as obuf)
    __shared__ __align__(16) uint32 raw32[RWORDS];               // 2904 B

    const int tid  = threadIdx.x;
    const int lane = tid & 63;
    const int wv   = tid >> 6;
    const int l15  = lane & 15;
    const int lg   = lane >> 4;
    const int hi   = lane >> 5;
    const int n32  = lane & 31;
    const int b      = blockIdx.z;
    const int h2base = blockIdx.y * TH2;
    const int t2base = blockIdx.x * TT2;

    const int L  = seq[b];
    const int L1 = ((L  - 1) >> 1) + 1;
    const int L2 = ((L1 - 1) >> 1) + 1;

    if (blockIdx.x == 0 && blockIdx.y == 0 && tid == 0)
        out[OUTN + b] = (float)L2;

    // ---- early-out: whole t-tile beyond L2 -> zeros (nt f32x4 stores) ----
    if (t2base >= L2) {
        const f32x4 z4 = (f32x4){0.f, 0.f, 0.f, 0.f};
#pragma unroll
        for (int k = 0; k < 2; ++k) {
            int i = tid + k * 256;                  // 64 rows (c2,r) x 8 quads
            int row = i >> 3, q = i & 7;
            int c2 = row >> 1, r = row & 1;
            int t2g = t2base + 4 * q;
            if (t2g < T2_)
                __builtin_nontemporal_store(z4,
                    (f32x4*)(out + ((b * C2_ + c2) * H2_ + h2base + r) * T2_ + t2g));
        }
        return;
    }

    // ---- phase 0: stage raw tile as packed bf16 pairs (branch-free, coalesced) ----
    const int row0 = 4 * h2base - 3;
    const int t0   = 4 * t2base - 3;
    const float* inb = in + b * (H_IN * T_IN);
#pragma unroll
    for (int k = 0; k < 3; ++k) {
        int pi = tid + k * 256;
        if (pi < RWORDS) {
            int row = pi / RCOLSW;
            int q   = pi - row * RCOLSW;
            int h = row0 + row;
            int t = t0 + 2 * q;
            bool hok = (h >= 0) & (h < H_IN);
            bool ok0 = hok & (t >= 0) & (t < T_IN);
            bool ok1 = hok & (t + 1 >= 0) & (t + 1 < T_IN);
            float v0 = inb[ok0 ? h * T_IN + t     : 0];
            float v1 = inb[ok1 ? h * T_IN + t + 1 : 0];
            v0 = ok0 ? v0 : 0.0f;
            v1 = ok1 ? v1 : 0.0f;
            raw32[pi] = (uint32)f2bf(v0) | ((uint32)f2bf(v1) << 16);
        }
    }

    // prefetch all weight fragments (overlaps staging latency)
    const short8 w1f = *((const short8*)ws + WS_W1OFF + lane);
    const int mt    = wv & 1;
    const int strip = wv >> 1;
    short8 afr[9];
#pragma unroll
    for (int tap = 0; tap < 9; ++tap)
        afr[tap] = *((const short8*)ws + (mt * 9 + tap) * 64 + lane);
    float b2r[4];
#pragma unroll
    for (int j = 0; j < 4; ++j) b2r[j] = b2[mt * 16 + lg * 4 + j];

    __syncthreads();

    // ---- phase 1: conv1 via MFMA 32x32x16; chunk = 32 positions ----
    const int h1base = 2 * h2base - 1;
    const int t1base = 2 * t2base - 1;
    for (int c = wv; c < NCHUNK; c += 4) {
        int p  = c * 32 + n32;
        int pc = p < NPOS ? p : NPOS - 1;
        int h1r = pc / NT1;
        int t1r = pc - h1r * NT1;

        const uint32* rp = raw32 + (2 * h1r) * RCOLSW + t1r;
        uint32 a0 = rp[0],            b0v = rp[1];
        uint32 a1 = rp[RCOLSW],       b1v = rp[RCOLSW + 1];
        uint32 a2 = rp[2 * RCOLSW],   b2v = rp[2 * RCOLSW + 1];

        // lo lanes: k0..7 = taps (0,0),(0,1),(0,2),(1,0),(1,1),(1,2),(2,0),(2,1)
        uint32 w0l = a0;
        uint32 w1l = (b0v & 0xffffu) | (a1 << 16);
        uint32 w2l = (a1 >> 16) | (b1v << 16);
        uint32 w3l = a2;
        // hi lanes: k8 = tap (2,2), k9 = 1.0 (bias), rest 0
        uint32 w0h = (b2v & 0xffffu) | 0x3f800000u;

        uint32 fw0 = hi ? w0h : w0l;
        uint32 fw1 = hi ? 0u  : w1l;
        uint32 fw2 = hi ? 0u  : w2l;
        uint32 fw3 = hi ? 0u  : w3l;
        short8 bfrag = __builtin_bit_cast(short8, (u32x4){fw0, fw1, fw2, fw3});

        f32x16 acc = {};
        acc = __builtin_amdgcn_mfma_f32_32x32x16_bf16(w1f, bfrag, acc, 0, 0, 0);

        // epilogue: relu + mask -> bf16 -> x1 LDS (lane holds 16 channels of one position)
        int h1 = h1base + h1r;
        int t1 = t1base + t1r;
        bool okp = (h1 >= 0) && (t1 >= 0) && (t1 < L1);
        if (p < NPOS) {
#pragma unroll
            for (int g = 0; g < 4; ++g) {
                float v0 = okp ? fmaxf(acc[4 * g + 0], 0.0f) : 0.0f;
                float v1 = okp ? fmaxf(acc[4 * g + 1], 0.0f) : 0.0f;
                float v2 = okp ? fmaxf(acc[4 * g + 2], 0.0f) : 0.0f;
                float v3 = okp ? fmaxf(acc[4 * g + 3], 0.0f) : 0.0f;
                u32x2 dw;
                dw.x = (uint32)f2bf(v0) | ((uint32)f2bf(v1) << 16);
                dw.y = (uint32)f2bf(v2) | ((uint32)f2bf(v3) << 16);
                *(u32x2*)(x1mem + x1off(h1r, t1r, g) + hi * 8) = dw;
            }
        }
    }

    __syncthreads();

    // ---- phase 2: conv2 implicit GEMM (16x16x32). wave = (strip, mt), rows internal ----
    f32x4 acc2[TH2];
#pragma unroll
    for (int r = 0; r < TH2; ++r) acc2[r] = (f32x4){0.f, 0.f, 0.f, 0.f};

#pragma unroll
    for (int tap = 0; tap < 9; ++tap) {
        const int kh = tap / 3;
        const int kt = tap % 3;
        const int t1r = 2 * (strip * 16 + l15) + kt;
#pragma unroll
        for (int r = 0; r < TH2; ++r) {
            short8 bx = *(const short8*)(x1mem + x1off(2 * r + kh, t1r, lg));
            acc2[r] = __builtin_amdgcn_mfma_f32_16x16x32_bf16(afr[tap], bx, acc2[r], 0, 0, 0);
        }
    }

    __syncthreads();   // x1 reads done; reuse x1mem as obuf [64 rows][OSTR]

    // D layout: col(l15)=t2 within strip, row=(lg*4+j)=c2 within mtile
    float* obuf = (float*)x1mem;
    {
        const int t2 = t2base + strip * 16 + l15;
        const bool vm = (t2 < L2);
#pragma unroll
        for (int r = 0; r < TH2; ++r) {
#pragma unroll
            for (int j = 0; j < 4; ++j) {
                int c2 = mt * 16 + lg * 4 + j;
                float v = acc2[r][j] + b2r[j];
                v = vm ? fmaxf(v, 0.0f) : 0.0f;
                obuf[(c2 * TH2 + r) * OSTR + strip * 16 + l15] = v;
            }
        }
    }
    __syncthreads();

    // ---- nt f32x4 stores: 1KB/wave segments, bypass L2 ----
#pragma unroll
    for (int k = 0; k < 2; ++k) {
        int i = tid + k * 256;                  // 64 rows x 8 quads
        int row = i >> 3, q = i & 7;
        int c2 = row >> 1, r = row & 1;
        int t2g = t2base + 4 * q;
        f32x4 v = *(const f32x4*)(obuf + row * OSTR + 4 * q);
        if (t2g < T2_)
            __builtin_nontemporal_store(v,
                (f32x4*)(out + ((b * C2_ + c2) * H2_ + h2base + r) * T2_ + t2g));
    }
}

extern "C" void kernel_launch(void* const* d_in, const int* in_sizes, int n_in,
                              void* d_out, int out_size, void* d_ws, size_t ws_size,
                              hipStream_t stream) {
    const float* in  = (const float*)d_in[0];
    const int*   seq = (const int*)d_in[1];
    const float* W1  = (const float*)d_in[2];
    const float* b1  = (const float*)d_in[3];
    const float* W2  = (const float*)d_in[4];
    const float* b2  = (const float*)d_in[5];
    float* out = (float*)d_out;
    unsigned short* ws = (unsigned short*)d_ws;

    wprep<<<dim3((WS_TOTAL + 255) / 256), dim3(256), 0, stream>>>(W2, W1, b1, ws);

    dim3 grid((T2_ + TT2 - 1) / TT2, H2_ / TH2, B_);   // 13 x 10 x 32
    fused_conv<<<grid, dim3(256), 0, stream>>>(in, seq, b2, ws, out);
}